// Round 7
// baseline (239.172 us; speedup 1.0000x reference)
//
#include <hip/hip_runtime.h>
#include <hip/hip_bf16.h>

#define N_NODES 100000
#define E_EDGES 800000
#define LN_EPS 1e-5f
#define WPAD 264           // 256 + 8 bf16 pad -> max 2-way LDS bank aliasing (free)

#define P_BLOCKS 512       // partition blocks
#define EPB 1563           // max edges per partition block (512*1563 >= 800000)
#define SLICE 64           // nodes per bucket (bk = dst>>6)
#define NBK 1563           // ceil(100000/64)
#define NBK_PAD 1792       // 7*256 (scan convenience)
#define OFFS_STRIDE 1564   // per-run stored starts incl sentinel
#define QCAP 768           // bucket edge capacity (mean 512, sd ~23 -> 11 sigma)
#define CONV_PER_BLOCK 12500   // 3.2M float4 groups of x / 256 convert blocks

typedef __attribute__((ext_vector_type(4))) float f32x4;
typedef __attribute__((ext_vector_type(8))) short short8;

__device__ __forceinline__ unsigned short f2bf(float f) {
    __hip_bfloat16 h = __float2bfloat16(f);
    return *reinterpret_cast<unsigned short*>(&h);
}
__device__ __forceinline__ float bflo(unsigned int u) { return __uint_as_float(u << 16); }
__device__ __forceinline__ float bfhi(unsigned int u) { return __uint_as_float(u & 0xffff0000u); }

// ---- pass 1: LDS counting-sort of edges by bucket, coalesced writeback ------
// Blocks [0,512): sort ~1563 edges each by dst bucket; write block-major
// sorted u32 records + per-bucket start offsets. Blocks [512,768): x->bf16.
// No global atomics. 5 barriers (wave-shfl scan, no Hillis-Steele).
__global__ __launch_bounds__(256) void fill_part1(
    const float* __restrict__ x, const int* __restrict__ ei,
    unsigned short* __restrict__ xb, unsigned int* __restrict__ gstore,
    unsigned short* __restrict__ offs)
{
    const int t = threadIdx.x, b = blockIdx.x;
    if (b >= P_BLOCKS) {                 // streaming convert half of the grid
        const float4* x4 = reinterpret_cast<const float4*>(x);
        ushort4* xb4 = reinterpret_cast<ushort4*>(xb);
        const int j0 = (b - P_BLOCKS) * CONV_PER_BLOCK;
        for (int j = t; j < CONV_PER_BLOCK; j += 256) {
            float4 v = x4[j0 + j];
            ushort4 o;
            o.x = f2bf(v.x); o.y = f2bf(v.y); o.z = f2bf(v.z); o.w = f2bf(v.w);
            xb4[j0 + j] = o;
        }
        return;
    }
    __shared__ unsigned int sorted_l[EPB];    // 6,252 B
    __shared__ int hist[NBK_PAD];             // 7,168 B (hist -> starts -> ends)
    __shared__ int wsum[4];
    const int lane = t & 63, wid = t >> 6;
    const int e0 = b * EPB;
    const int ne = (e0 + EPB <= E_EDGES) ? EPB : (E_EDGES - e0);  // tail block
    for (int i = t; i < NBK_PAD; i += 256) hist[i] = 0;
    __syncthreads();
    for (int i = t; i < ne; i += 256)          // pass 1: histogram dst (L1-res)
        atomicAdd(&hist[((unsigned)ei[E_EDGES + e0 + i]) >> 6], 1);
    __syncthreads();
    // exclusive scan of 1792 buckets: thread t owns [7t, 7t+7)
    int h[7], s = 0;
#pragma unroll
    for (int k = 0; k < 7; ++k) { h[k] = hist[t * 7 + k]; s += h[k]; }
    int inc = s;                               // wave-inclusive shfl scan
#pragma unroll
    for (int off = 1; off < 64; off <<= 1) {
        int u = __shfl_up(inc, off);
        if (lane >= off) inc += u;
    }
    if (lane == 63) wsum[wid] = inc;
    __syncthreads();
    int wbase = 0;
#pragma unroll
    for (int w = 0; w < 4; ++w) if (w < wid) wbase += wsum[w];
    int run = wbase + inc - s;                 // exclusive prefix of bucket 7t
#pragma unroll
    for (int k = 0; k < 7; ++k) {
        int idx = t * 7 + k;
        if (idx < OFFS_STRIDE) offs[b * OFFS_STRIDE + idx] = (unsigned short)run;
        hist[idx] = run;                       // in-place starts
        run += h[k];
    }
    __syncthreads();
    for (int i = t; i < ne; i += 256) {        // pass 2: scatter (edges L1-hot)
        unsigned src = (unsigned)ei[e0 + i];
        unsigned dst = (unsigned)ei[E_EDGES + e0 + i];
        int p = atomicAdd(&hist[dst >> 6], 1);
        sorted_l[p] = (src << 6) | (dst & 63u);
    }
    __syncthreads();
    for (int i = t; i < ne; i += 256)          // coalesced writeback
        gstore[b * EPB + i] = sorted_l[i];
}

// ---- pass 2: per-bucket LDS sort -> 8-edge-wide register gather -------------
// Two blocks per bucket (feature halves). Block (b,half) owns nodes
// [64b, 64b+64) x features [64*half, 64*half+64). Lane = subi(8 edges) x
// chunk(8 x 16B): one uint4 load covers 8 neighbor rows -> a degree-8 node
// gathers in ONE load round. Exact degree (no CAP truncation).
__global__ __launch_bounds__(256) void agg2(
    const unsigned int* __restrict__ gstore, const unsigned short* __restrict__ offs,
    const unsigned short* __restrict__ xb, unsigned short* __restrict__ nb)
{
    __shared__ unsigned int sortedq[QCAP];   // 3,072 B
    __shared__ int cnt_l[SLICE];
    __shared__ int run_l[SLICE];
    __shared__ int qs_l[SLICE + 1];
    const int t = threadIdx.x;
    const int b = blockIdx.x >> 1, half = blockIdx.x & 1;
    if (t < SLICE) { cnt_l[t] = 0; run_l[t] = 0; }
    __syncthreads();
    int s0[2], s1[2];
#pragma unroll
    for (int u = 0; u < 2; ++u) {            // thread handles runs t, t+256
        int rr = t + u * 256;
        s0[u] = offs[rr * OFFS_STRIDE + b];
        s1[u] = offs[rr * OFFS_STRIDE + b + 1];
    }
#pragma unroll
    for (int u = 0; u < 2; ++u) {            // pass A: histogram by node
        const unsigned int* myrun = gstore + (t + u * 256) * EPB;
        for (int j = s0[u]; j < s1[u]; ++j)
            atomicAdd(&cnt_l[myrun[j] & 63u], 1);
    }
    __syncthreads();
    if (t < SLICE) {                         // wave-0 shfl scan of 64 counts
        int inc = cnt_l[t];
        for (int off = 1; off < 64; off <<= 1) {
            int u = __shfl_up(inc, off);
            if (t >= off) inc += u;
        }
        qs_l[t + 1] = inc;
        if (t == 0) qs_l[0] = 0;
    }
    __syncthreads();
#pragma unroll
    for (int u = 0; u < 2; ++u) {            // pass B: scatter (L2-hot reread)
        const unsigned int* myrun = gstore + (t + u * 256) * EPB;
        for (int j = s0[u]; j < s1[u]; ++j) {
            unsigned rec = myrun[j];
            int p = qs_l[rec & 63u] + atomicAdd(&run_l[rec & 63u], 1);
            if (p < QCAP) sortedq[p] = rec;
        }
    }
    __syncthreads();
    // gather: wave owns 16 nodes; lane = subi(8 edges) x chunk(8 x 16B)
    const int wave = t >> 6, lane = t & 63;
    const int subi = lane >> 3, chunk = lane & 7;
    const int cbase = half * 8;              // uint4 offset of this feature half
    const uint4* x4 = reinterpret_cast<const uint4*>(xb);   // 16 uint4 per row
    for (int ln = wave * 16; ln < wave * 16 + 16; ++ln) {
        const int qb = qs_l[ln], cc = qs_l[ln + 1] - qb;
        float acc[8];
#pragma unroll
        for (int k = 0; k < 8; ++k) acc[k] = 0.f;
        for (int i = 0; i < cc; i += 8) {
            int idx = i + subi;
            if (idx < cc && qb + idx < QCAP) {
                unsigned rec = sortedq[qb + idx];
                uint4 v = x4[(rec >> 6) * 16 + cbase + chunk];
                acc[0] += bflo(v.x); acc[1] += bfhi(v.x);
                acc[2] += bflo(v.y); acc[3] += bfhi(v.y);
                acc[4] += bflo(v.z); acc[5] += bfhi(v.z);
                acc[6] += bflo(v.w); acc[7] += bfhi(v.w);
            }
        }
#pragma unroll
        for (int k = 0; k < 8; ++k) {        // sum the 8 subi groups
            acc[k] += __shfl_xor(acc[k], 8);
            acc[k] += __shfl_xor(acc[k], 16);
            acc[k] += __shfl_xor(acc[k], 32);
        }
        const int node = b * SLICE + ln;
        if (subi == 0 && node < N_NODES) {
            float inv = 1.0f / (float)(cc > 1 ? cc : 1);
            uint4 o;
            o.x = ((unsigned)f2bf(acc[1] * inv) << 16) | f2bf(acc[0] * inv);
            o.y = ((unsigned)f2bf(acc[3] * inv) << 16) | f2bf(acc[2] * inv);
            o.z = ((unsigned)f2bf(acc[5] * inv) << 16) | f2bf(acc[4] * inv);
            o.w = ((unsigned)f2bf(acc[7] * inv) << 16) | f2bf(acc[6] * inv);
            reinterpret_cast<uint4*>(nb)[node * 16 + cbase + chunk] = o;
        }
    }
}

// ---- MFMA GEMM (K=256 over [x|neigh]) + bias + ReLU + LayerNorm ------------
// Block = 256 thr = 4 waves; wave owns 64 rows x 128 cols.
// A-frag: A[m=lane&15][k=quad*8+j]; C/D: col=lane&15, row=quad*4+reg.
__global__ __launch_bounds__(256, 2) void fused_mfma(
    const unsigned short* __restrict__ xb, const unsigned short* __restrict__ nb,
    const float* __restrict__ Wself, const float* __restrict__ Wneigh,
    const float* __restrict__ bias, const float* __restrict__ gamma,
    const float* __restrict__ beta, float* __restrict__ out)
{
    __shared__ unsigned short WT[128][WPAD];   // [out_col][kk]; kk<128: Ws, else Wn
    const int t = threadIdx.x;
    const float4* Ws4 = reinterpret_cast<const float4*>(Wself);
    const float4* Wn4 = reinterpret_cast<const float4*>(Wneigh);
    for (int idx = t; idx < 4096; idx += 256) {
        int n = idx >> 5, k4 = (idx & 31) << 2;     // W is [n][k], coalesced read
        float4 a = Ws4[idx];
        float4 b = Wn4[idx];
        ushort4 ua, ub;
        ua.x = f2bf(a.x); ua.y = f2bf(a.y); ua.z = f2bf(a.z); ua.w = f2bf(a.w);
        ub.x = f2bf(b.x); ub.y = f2bf(b.y); ub.z = f2bf(b.z); ub.w = f2bf(b.w);
        *reinterpret_cast<ushort4*>(&WT[n][k4]) = ua;
        *reinterpret_cast<ushort4*>(&WT[n][128 + k4]) = ub;
    }
    __syncthreads();

    const int lane = t & 63, wave = t >> 6;
    const int l16 = lane & 15, quad = lane >> 4;
    float bia[8], gam[8], bet[8];
#pragma unroll
    for (int n = 0; n < 8; ++n) {
        int col = n * 16 + l16;
        bia[n] = bias[col]; gam[n] = gamma[col]; bet[n] = beta[col];
    }

    const int ntiles = (N_NODES + 255) / 256;
    for (int tile = blockIdx.x; tile < ntiles; tile += gridDim.x) {
        const int rowbase = tile * 256 + wave * 64;
        f32x4 acc[4][8];
#pragma unroll
        for (int m = 0; m < 4; ++m)
#pragma unroll
            for (int n = 0; n < 8; ++n) acc[m][n] = (f32x4)0.f;
        int rows[4];
#pragma unroll
        for (int m = 0; m < 4; ++m) {
            int r = rowbase + m * 16 + l16;
            rows[m] = r < N_NODES ? r : N_NODES - 1;   // tail clamp; store guarded
        }
#pragma unroll
        for (int kstep = 0; kstep < 8; ++kstep) {
            const unsigned short* Asrc = (kstep < 4) ? xb : nb;
            const int koff = (kstep & 3) * 32 + quad * 8;
            short8 a[4];
#pragma unroll
            for (int m = 0; m < 4; ++m)
                a[m] = *reinterpret_cast<const short8*>(Asrc + rows[m] * 128 + koff);
#pragma unroll
            for (int n = 0; n < 8; ++n) {
                short8 b = *reinterpret_cast<const short8*>(&WT[n * 16 + l16][kstep * 32 + quad * 8]);
#pragma unroll
                for (int m = 0; m < 4; ++m)
                    acc[m][n] = __builtin_amdgcn_mfma_f32_16x16x32_bf16(a[m], b, acc[m][n], 0, 0, 0);
            }
        }
        // epilogue: bias+ReLU+LN; row R's 128 cols live in the 16 lanes of one quad
#pragma unroll
        for (int m = 0; m < 4; ++m) {
#pragma unroll
            for (int r = 0; r < 4; ++r) {
                float h[8], s = 0.f, q = 0.f;
#pragma unroll
                for (int n = 0; n < 8; ++n) {
                    float v = acc[m][n][r] + bia[n];
                    v = fmaxf(v, 0.f);
                    h[n] = v; s += v; q += v * v;
                }
#pragma unroll
                for (int msk = 1; msk <= 8; msk <<= 1) {
                    s += __shfl_xor(s, msk);
                    q += __shfl_xor(q, msk);
                }
                const float mu = s * (1.f / 128.f);
                const float var = q * (1.f / 128.f) - mu * mu;
                const float rs = rsqrtf(var + LN_EPS);
                const int R = rowbase + m * 16 + quad * 4 + r;
                if (R < N_NODES) {
#pragma unroll
                    for (int n = 0; n < 8; ++n)
                        out[R * 128 + n * 16 + l16] = (h[n] - mu) * rs * gam[n] + bet[n];
                }
            }
        }
    }
}

extern "C" void kernel_launch(void* const* d_in, const int* in_sizes, int n_in,
                              void* d_out, int out_size, void* d_ws, size_t ws_size,
                              hipStream_t stream) {
    const float* x      = (const float*)d_in[0];
    const int*   ei     = (const int*)d_in[1];
    const float* Wself  = (const float*)d_in[2];
    const float* Wneigh = (const float*)d_in[3];
    const float* bias   = (const float*)d_in[4];
    const float* gamma  = (const float*)d_in[5];
    const float* beta   = (const float*)d_in[6];
    float* out = (float*)d_out;

    // ws layout (~56 MB used)
    char* ws = (char*)d_ws;
    unsigned short* xb = (unsigned short*)ws;                       // 25,600,000
    unsigned short* nb = (unsigned short*)(ws + 25600000);          // 25,600,000
    unsigned int* gstore = (unsigned int*)(ws + 51200000);          //  3,201,024
    unsigned short* offs = (unsigned short*)(ws + 54401024);        //  1,601,536

    fill_part1<<<P_BLOCKS + 256, 256, 0, stream>>>(x, ei, xb, gstore, offs);
    agg2<<<2 * NBK, 256, 0, stream>>>(gstore, offs, xb, nb);
    const int ntiles = (N_NODES + 255) / 256;
    fused_mfma<<<ntiles, 256, 0, stream>>>(xb, nb, Wself, Wneigh, bias, gamma, beta, out);
}